// Round 1
// baseline (246.432 us; speedup 1.0000x reference)
//
#include <hip/hip_runtime.h>

// IntegerNeuron: T-step leaky-integrate-fire-style scan over [T,B,C,H,W].
// T=8, B=32, C=128, H=32, W=32. Memory-bound: 128 MiB in + 128 MiB out.
//
// Numerics: must be bit-exact vs the fp32 reference because spike = (mem >=
// vth_scaled) is a hard threshold. Reference op order:
//   drive = x * tau            (separate elementwise multiply)
//   mem   = (mem + drive) + bias_scaled
//   spike = mem >= vth_scaled
//   mem   = mem - spike * vth_scaled
// tau == 4.0 (power of two) => x*tau exact => any compiler FMA contraction of
// (mem + x*tau) is bit-identical to mul-then-add. Additions are never
// reassociated at -O3 without -ffast-math. jnp.round == half-to-even == rintf.

constexpr int T_STEPS = 8;
constexpr int NB = 32, NC = 128, NH = 32, NW = 32;
constexpr int NSP = NB * NC * NH * NW;   // 4,194,304 spatial positions
constexpr int N4  = NSP / 4;             // 1,048,576 float4 positions
constexpr int HW4 = (NH * NW) / 4;       // 256 float4 per (b,c) plane

__global__ __launch_bounds__(256) void IntegerNeuron_84842783965742_kernel(
    const float4* __restrict__ x,        // [T, B, C, H, W] as float4
    const float*  __restrict__ prev_scale,  // [C]
    const float*  __restrict__ prev_bias,   // [C]
    const float*  __restrict__ vth,         // scalar
    const int*    __restrict__ tau,         // scalar int
    const int*    __restrict__ is_first,    // scalar int
    float4*       __restrict__ out)         // [T, B, C, H, W] as float4
{
    const int i = blockIdx.x * blockDim.x + threadIdx.x;   // float4 index
    const int c = (i / HW4) % NC;                          // channel (4 elems share it)

    const float tau_f = (float)tau[0];
    const float denom = prev_scale[c] + 1e-12f;
    const float bs = rintf(prev_bias[c] * tau_f / denom);  // bias_scaled[c]
    const float vs = rintf(vth[0] * tau_f / denom);        // vth_scaled[c]
    const float mul = is_first[0] ? 1.0f : tau_f;          // drive multiplier

    float m0 = 0.0f, m1 = 0.0f, m2 = 0.0f, m3 = 0.0f;      // mem carried in VGPRs

    #pragma unroll
    for (int t = 0; t < T_STEPS; ++t) {
        const float4 xv = x[(size_t)t * N4 + i];

        // mem = (mem + x*tau) + bias_scaled  — matches reference association.
        m0 = (m0 + xv.x * mul) + bs;
        m1 = (m1 + xv.y * mul) + bs;
        m2 = (m2 + xv.z * mul) + bs;
        m3 = (m3 + xv.w * mul) + bs;

        float4 sp;
        sp.x = (m0 >= vs) ? 1.0f : 0.0f;
        sp.y = (m1 >= vs) ? 1.0f : 0.0f;
        sp.z = (m2 >= vs) ? 1.0f : 0.0f;
        sp.w = (m3 >= vs) ? 1.0f : 0.0f;

        // soft reset: spike and vs are integer-valued, product exact.
        m0 -= sp.x * vs;
        m1 -= sp.y * vs;
        m2 -= sp.z * vs;
        m3 -= sp.w * vs;

        out[(size_t)t * N4 + i] = sp;
    }
}

extern "C" void kernel_launch(void* const* d_in, const int* in_sizes, int n_in,
                              void* d_out, int out_size, void* d_ws, size_t ws_size,
                              hipStream_t stream) {
    const float4* x          = (const float4*)d_in[0];
    const float*  prev_scale = (const float*)d_in[1];
    const float*  prev_bias  = (const float*)d_in[2];
    const float*  vth        = (const float*)d_in[3];
    const int*    tau        = (const int*)d_in[4];
    const int*    is_first   = (const int*)d_in[5];
    float4*       out        = (float4*)d_out;

    dim3 block(256);
    dim3 grid(N4 / 256);   // 4096 blocks
    IntegerNeuron_84842783965742_kernel<<<grid, block, 0, stream>>>(
        x, prev_scale, prev_bias, vth, tau, is_first, out);
}